// Round 9
// baseline (550.902 us; speedup 1.0000x reference)
//
#include <hip/hip_runtime.h>
#include <hip/hip_bf16.h>

typedef unsigned short u16;
typedef unsigned char u8;
typedef short short8 __attribute__((ext_vector_type(8)));
typedef float floatx4 __attribute__((ext_vector_type(4)));
typedef float floatx2 __attribute__((ext_vector_type(2)));

__device__ __forceinline__ float b2f(u16 u) {
    unsigned v = ((unsigned)u) << 16;
    float f;
    __builtin_memcpy(&f, &v, 4);
    return f;
}
__device__ __forceinline__ float b2f_lo(unsigned w) { return b2f((u16)(w & 0xffffu)); }
__device__ __forceinline__ float b2f_hi(unsigned w) { return b2f((u16)(w >> 16)); }
__device__ __forceinline__ u16 f2b(float f) {
    unsigned u;
    __builtin_memcpy(&u, &f, 4);
    u = u + 0x7fffu + ((u >> 16) & 1u);
    return (u16)(u >> 16);
}
__device__ __forceinline__ unsigned pack2(float a, float b) {
    return (unsigned)f2b(a) | ((unsigned)f2b(b) << 16);
}
__device__ __forceinline__ float loadp(const void* p, int i, int f) {
    return f ? ((const float*)p)[i] : b2f(((const u16*)p)[i]);
}
__device__ __forceinline__ u8 f2e4m3(float v) {
    int r = __builtin_amdgcn_cvt_pk_fp8_f32(v, v, 0, false);
    return (u8)(r & 0xff);
}
__device__ __forceinline__ void acc16_fp8(float* a, uint4 p) {
    floatx2 f;
    f = __builtin_amdgcn_cvt_pk_f32_fp8((int)p.x, false); a[0] += f[0];  a[1] += f[1];
    f = __builtin_amdgcn_cvt_pk_f32_fp8((int)p.x, true);  a[2] += f[0];  a[3] += f[1];
    f = __builtin_amdgcn_cvt_pk_f32_fp8((int)p.y, false); a[4] += f[0];  a[5] += f[1];
    f = __builtin_amdgcn_cvt_pk_f32_fp8((int)p.y, true);  a[6] += f[0];  a[7] += f[1];
    f = __builtin_amdgcn_cvt_pk_f32_fp8((int)p.z, false); a[8] += f[0];  a[9] += f[1];
    f = __builtin_amdgcn_cvt_pk_f32_fp8((int)p.z, true);  a[10] += f[0]; a[11] += f[1];
    f = __builtin_amdgcn_cvt_pk_f32_fp8((int)p.w, false); a[12] += f[0]; a[13] += f[1];
    f = __builtin_amdgcn_cvt_pk_f32_fp8((int)p.w, true);  a[14] += f[0]; a[15] += f[1];
}

// ---------------- dtype sniffing ----------------
__global__ void sniff_kernel(const unsigned* __restrict__ xw, const int* __restrict__ eiw,
                             int* __restrict__ flags) {
    __shared__ int s_fp32, s_i64;
    if (threadIdx.x == 0) { s_fp32 = 0; s_i64 = 1; }
    __syncthreads();
    int t = threadIdx.x;  // 256 threads
    unsigned w = xw[t];
    float lo = b2f_lo(w);
    if (!(fabsf(lo) <= 64.0f)) atomicOr(&s_fp32, 1);   // also catches NaN
    if (eiw[2 * t + 1] != 0) atomicAnd(&s_i64, 0);
    __syncthreads();
    if (t == 0) { flags[0] = s_fp32; flags[1] = s_i64; }
}

// ---------------- input conversion (bf16 + fp8 shadow) ----------------
__global__ void cvt_x_kernel(const void* __restrict__ x, u16* __restrict__ xb,
                             u16* __restrict__ x8,
                             const int* __restrict__ flags, int nPairs) {
    int f = flags[0];
    int i = blockIdx.x * 256 + threadIdx.x;
    if (i >= nPairs) return;
    float lo, hi;
    if (f) {
        float2 v = ((const float2*)x)[i];
        lo = v.x; hi = v.y;
        ((unsigned*)xb)[i] = pack2(lo, hi);
    } else {
        unsigned w = ((const unsigned*)x)[i];
        lo = b2f_lo(w); hi = b2f_hi(w);
        ((unsigned*)xb)[i] = w;
    }
    int r = __builtin_amdgcn_cvt_pk_fp8_f32(lo, hi, 0, false);
    x8[i] = (u16)(r & 0xffff);
}

// ---------------- fused parameter prep: all weights stored TRANSPOSED Wt[n][k] ----------------
__global__ void prep_all_kernel(const void* Wl1, const void* Wr1, u16* __restrict__ W1t,
                                const void* Wl2, const void* Wr2, u16* __restrict__ W2t,
                                const void* Wl3, const void* Wr3, u16* __restrict__ W3t,
                                const void* We1, u16* __restrict__ Webt,
                                const void* g1, const void* b1, const void* bl1,
                                float* __restrict__ al1, float* __restrict__ bt1,
                                const void* g2, const void* b2, const void* bl2,
                                float* __restrict__ al2, float* __restrict__ bt2,
                                const void* bl3,
                                float* __restrict__ al3, float* __restrict__ bt3,
                                const void* be1, const void* We2, const void* be2,
                                float* __restrict__ dparams,
                                const int* __restrict__ flags) {
    int f = flags[0];
    int idx = blockIdx.x * 256 + threadIdx.x;
    if (idx < 32768) {                       // W1t[n*256+k] = k<128 ? Wl1[k][n] : Wr1[k-128][n]
        int n = idx >> 8, k = idx & 255;
        const void* src = (k < 128) ? Wl1 : Wr1;
        int j = (k & 127) * 128 + n;
        W1t[idx] = f ? f2b(((const float*)src)[j]) : ((const u16*)src)[j];
    } else if (idx < 65536) {
        int i = idx - 32768;
        int n = i >> 8, k = i & 255;
        const void* src = (k < 128) ? Wl2 : Wr2;
        int j = (k & 127) * 128 + n;
        W2t[i] = f ? f2b(((const float*)src)[j]) : ((const u16*)src)[j];
    } else if (idx < 81920) {                // W3t[n*128+k]: n<64 from Wl3, else Wr3
        int i = idx - 65536;
        int n = i >> 7, k = i & 127;
        const void* src = (n < 64) ? Wl3 : Wr3;
        int j = k * 64 + (n & 63);
        W3t[i] = f ? f2b(((const float*)src)[j]) : ((const u16*)src)[j];
    } else if (idx < 98304) {                // Webt[n*128+k] = We1[k][n]
        int i = idx - 81920;
        int n = i >> 7, k = i & 127;
        int j = k * 128 + n;
        Webt[i] = f ? f2b(((const float*)We1)[j]) : ((const u16*)We1)[j];
    } else {
        int i = idx - 98304;
        if (i < 128) {
            float s = loadp(g1, i, f) * rsqrtf(1.0f + 1e-5f);
            al1[i] = s;
            bt1[i] = loadp(bl1, i, f) * s + loadp(b1, i, f);
        } else if (i < 256) {
            int j = i - 128;
            float s = loadp(g2, j, f) * rsqrtf(1.0f + 1e-5f);
            al2[j] = s;
            bt2[j] = loadp(bl2, j, f) * s + loadp(b2, j, f);
        } else if (i < 384) {
            int j = i - 256;
            al3[j] = 1.0f;
            bt3[j] = (j < 64) ? 0.0f : loadp(bl3, j - 64, f);
        } else if (i < 512) {
            int j = i - 384;
            dparams[j] = loadp(be1, j, f);
            dparams[128 + j] = loadp(We2, j, f);
            if (j == 0) dparams[256] = loadp(be2, 0, f);
        }
    }
}

// ---------------- CSR build: two-level counting sort (no global atomics) ----------------
__device__ __forceinline__ int edge_at(const int* ei, long long idx, int i64) {
    return i64 ? ei[2 * idx] : ei[idx];
}

__global__ __launch_bounds__(256) void bucket_count_kernel(const int* __restrict__ ei,
                                                           int* __restrict__ blockhist,
                                                           int E, int EPB, int B1, int nbuck,
                                                           const int* __restrict__ flags) {
    __shared__ int hist[1024];
    for (int i = threadIdx.x; i < nbuck; i += 256) hist[i] = 0;
    __syncthreads();
    int i64 = flags[1];
    int b = blockIdx.x;
    int lo = b * EPB, hi = min(lo + EPB, E);
    for (int e = lo + (int)threadIdx.x; e < hi; e += 256) {
        int d = edge_at(ei, (long long)E + e, i64);
        atomicAdd(&hist[d >> 7], 1);
    }
    __syncthreads();
    for (int k = threadIdx.x; k < nbuck; k += 256)
        blockhist[(size_t)k * B1 + b] = hist[k];
}

__global__ __launch_bounds__(64) void colscan_kernel(int* __restrict__ blockhist,
                                                     int* __restrict__ coltot, int B1) {
    int k = blockIdx.x, l = threadIdx.x;
    int* bh = blockhist + (size_t)k * B1;
    int x0 = (l < B1) ? bh[l] : 0;
    int x1 = (64 + l < B1) ? bh[64 + l] : 0;
    int s0 = x0;
    #pragma unroll
    for (int off = 1; off < 64; off <<= 1) {
        int u = __shfl_up(s0, off, 64);
        if (l >= off) s0 += u;
    }
    int tot0 = __shfl(s0, 63, 64);
    int s1 = x1;
    #pragma unroll
    for (int off = 1; off < 64; off <<= 1) {
        int u = __shfl_up(s1, off, 64);
        if (l >= off) s1 += u;
    }
    int tot1 = __shfl(s1, 63, 64);
    s1 += tot0;
    if (l < B1) bh[l] = s0 - x0;
    if (64 + l < B1) bh[64 + l] = s1 - x1;
    if (l == 0) coltot[k] = tot0 + tot1;
}

__global__ __launch_bounds__(1024) void base_scan_kernel(const int* __restrict__ coltot,
                                                         int* __restrict__ bucketbase,
                                                         int* __restrict__ rowptrN,
                                                         int nbuck, int E) {
    __shared__ int wsum[16];
    int t = threadIdx.x, lane = t & 63, w = t >> 6;
    int v = (t < nbuck) ? coltot[t] : 0;
    int inc = v;
    #pragma unroll
    for (int off = 1; off < 64; off <<= 1) {
        int u = __shfl_up(inc, off, 64);
        if (lane >= off) inc += u;
    }
    if (lane == 63) wsum[w] = inc;
    __syncthreads();
    int add = 0;
    for (int i = 0; i < w; ++i) add += wsum[i];
    if (t < nbuck) bucketbase[t] = add + inc - v;
    if (t == 0) rowptrN[0] = E;
}

__global__ __launch_bounds__(256) void bucket_scatter_kernel(const int* __restrict__ ei,
                                                             const int* __restrict__ bucketbase,
                                                             const int* __restrict__ blockhist,
                                                             int2* __restrict__ pairs,
                                                             int E, int EPB, int B1, int nbuck,
                                                             const int* __restrict__ flags) {
    __shared__ int off[1024];
    int b = blockIdx.x;
    for (int k = threadIdx.x; k < nbuck; k += 256)
        off[k] = bucketbase[k] + blockhist[(size_t)k * B1 + b];
    __syncthreads();
    int i64 = flags[1];
    int lo = b * EPB, hi = min(lo + EPB, E);
    for (int e = lo + (int)threadIdx.x; e < hi; e += 256) {
        int s = edge_at(ei, e, i64);
        int d = edge_at(ei, (long long)E + e, i64);
        int slot = atomicAdd(&off[d >> 7], 1);
        pairs[slot] = make_int2(s, d);
    }
}

__global__ __launch_bounds__(256) void bucket_csr_kernel(const int2* __restrict__ pairs,
                                                         const int* __restrict__ bucketbase,
                                                         const int* __restrict__ coltot,
                                                         int* __restrict__ rowptr,
                                                         int* __restrict__ col, int N) {
    __shared__ int srcs[4096];
    __shared__ unsigned char dl[4096];
    __shared__ int hist[128], cur[128];
    int k = blockIdx.x, tid = threadIdx.x;
    if (tid < 128) hist[tid] = 0;
    __syncthreads();
    int base = bucketbase[k], cnt = coltot[k];
    int staged = min(cnt, 4096);
    for (int i = tid; i < cnt; i += 256) {
        int2 pr = pairs[base + i];
        int j = pr.y & 127;
        atomicAdd(&hist[j], 1);
        if (i < 4096) { srcs[i] = pr.x; dl[i] = (unsigned char)j; }
    }
    __syncthreads();
    if (tid < 64) {
        int x0 = hist[tid], x1 = hist[64 + tid];
        int s0 = x0;
        #pragma unroll
        for (int off = 1; off < 64; off <<= 1) {
            int u = __shfl_up(s0, off, 64);
            if (tid >= off) s0 += u;
        }
        int tot0 = __shfl(s0, 63, 64);
        int s1 = x1;
        #pragma unroll
        for (int off = 1; off < 64; off <<= 1) {
            int u = __shfl_up(s1, off, 64);
            if (tid >= off) s1 += u;
        }
        s1 += tot0;
        cur[tid] = s0 - x0;
        cur[64 + tid] = s1 - x1;
    }
    __syncthreads();
    int node0 = k << 7;
    if (tid < 128 && node0 + tid < N) rowptr[node0 + tid] = base + cur[tid];
    __syncthreads();
    for (int i = tid; i < staged; i += 256) {
        int slot = base + atomicAdd(&cur[dl[i]], 1);
        col[slot] = srcs[i];
    }
    for (int i = 4096 + tid; i < cnt; i += 256) {
        int2 pr = pairs[base + i];
        int slot = base + atomicAdd(&cur[pr.y & 127], 1);
        col[slot] = pr.x;
    }
}

// ---------------- mean aggregation over fp8 rows -> bf16 means ----------------
template <int CH>
__global__ __launch_bounds__(256) void aggregate_fp8_kernel(const u8* __restrict__ X8,
                                                            const int* __restrict__ rowptr,
                                                            const int* __restrict__ col,
                                                            u16* __restrict__ meanout, int N) {
    constexpr int LPR = CH / 16;
    constexpr int GPB = 256 / LPR;
    int t = threadIdx.x;
    int g = t / LPR;
    int o = t % LPR;
    int u = blockIdx.x * GPB + g;
    if (u >= N) return;
    const uint4* Xv = (const uint4*)X8;
    int beg = rowptr[u], end = rowptr[u + 1];
    float a[16];
    #pragma unroll
    for (int i = 0; i < 16; ++i) a[i] = 0.f;
    int e = beg;
    for (; e + 4 <= end; e += 4) {
        int c0 = col[e], c1 = col[e + 1], c2 = col[e + 2], c3 = col[e + 3];
        uint4 p0 = Xv[(size_t)c0 * LPR + o];
        uint4 p1 = Xv[(size_t)c1 * LPR + o];
        uint4 p2 = Xv[(size_t)c2 * LPR + o];
        uint4 p3 = Xv[(size_t)c3 * LPR + o];
        acc16_fp8(a, p0); acc16_fp8(a, p1); acc16_fp8(a, p2); acc16_fp8(a, p3);
    }
    for (; e < end; ++e) {
        uint4 p = Xv[(size_t)col[e] * LPR + o];
        acc16_fp8(a, p);
    }
    int deg = end - beg;
    float inv = (deg > 0) ? 1.0f / (float)deg : 0.0f;
    uint4 ov0, ov1;
    ov0.x = pack2(a[0] * inv, a[1] * inv);   ov0.y = pack2(a[2] * inv, a[3] * inv);
    ov0.z = pack2(a[4] * inv, a[5] * inv);   ov0.w = pack2(a[6] * inv, a[7] * inv);
    ov1.x = pack2(a[8] * inv, a[9] * inv);   ov1.y = pack2(a[10] * inv, a[11] * inv);
    ov1.z = pack2(a[12] * inv, a[13] * inv); ov1.w = pack2(a[14] * inv, a[15] * inv);
    uint4* mo = (uint4*)meanout;
    mo[(size_t)u * (CH / 8) + o * 2 + 0] = ov0;
    mo[(size_t)u * (CH / 8) + o * 2 + 1] = ov1;
}

// ---------------- fused layer-3 tail: z = mean_fp8(t8) + u ----------------
__global__ __launch_bounds__(256) void agg_combine_kernel(const u8* __restrict__ T8,
                                                          const int* __restrict__ rowptr,
                                                          const int* __restrict__ col,
                                                          const u16* __restrict__ ubuf,
                                                          u16* __restrict__ zbuf,
                                                          void* __restrict__ dout,
                                                          int N, const int* __restrict__ flags) {
    constexpr int LPR = 4;
    constexpr int GPB = 64;
    int f = flags[0];
    int t = threadIdx.x;
    int g = t / LPR;
    int o = t % LPR;
    int u = blockIdx.x * GPB + g;
    if (u >= N) return;
    const uint4* Xv = (const uint4*)T8;
    int beg = rowptr[u], end = rowptr[u + 1];
    float a[16];
    #pragma unroll
    for (int i = 0; i < 16; ++i) a[i] = 0.f;
    int e = beg;
    for (; e + 4 <= end; e += 4) {
        int c0 = col[e], c1 = col[e + 1], c2 = col[e + 2], c3 = col[e + 3];
        uint4 p0 = Xv[(size_t)c0 * LPR + o];
        uint4 p1 = Xv[(size_t)c1 * LPR + o];
        uint4 p2 = Xv[(size_t)c2 * LPR + o];
        uint4 p3 = Xv[(size_t)c3 * LPR + o];
        acc16_fp8(a, p0); acc16_fp8(a, p1); acc16_fp8(a, p2); acc16_fp8(a, p3);
    }
    for (; e < end; ++e) {
        uint4 p = Xv[(size_t)col[e] * LPR + o];
        acc16_fp8(a, p);
    }
    int deg = end - beg;
    float inv = (deg > 0) ? 1.0f / (float)deg : 0.0f;
    const uint4* uv = (const uint4*)(ubuf + (size_t)u * 64 + o * 16);
    uint4 u0 = uv[0], u1 = uv[1];
    float z[16];
    z[0] = a[0] * inv + b2f_lo(u0.x);  z[1] = a[1] * inv + b2f_hi(u0.x);
    z[2] = a[2] * inv + b2f_lo(u0.y);  z[3] = a[3] * inv + b2f_hi(u0.y);
    z[4] = a[4] * inv + b2f_lo(u0.z);  z[5] = a[5] * inv + b2f_hi(u0.z);
    z[6] = a[6] * inv + b2f_lo(u0.w);  z[7] = a[7] * inv + b2f_hi(u0.w);
    z[8] = a[8] * inv + b2f_lo(u1.x);  z[9] = a[9] * inv + b2f_hi(u1.x);
    z[10] = a[10] * inv + b2f_lo(u1.y); z[11] = a[11] * inv + b2f_hi(u1.y);
    z[12] = a[12] * inv + b2f_lo(u1.z); z[13] = a[13] * inv + b2f_hi(u1.z);
    z[14] = a[14] * inv + b2f_lo(u1.w); z[15] = a[15] * inv + b2f_hi(u1.w);
    uint4 zv0, zv1;
    zv0.x = pack2(z[0], z[1]);   zv0.y = pack2(z[2], z[3]);
    zv0.z = pack2(z[4], z[5]);   zv0.w = pack2(z[6], z[7]);
    zv1.x = pack2(z[8], z[9]);   zv1.y = pack2(z[10], z[11]);
    zv1.z = pack2(z[12], z[13]); zv1.w = pack2(z[14], z[15]);
    uint4* zo = (uint4*)(zbuf + (size_t)u * 64 + o * 16);
    zo[0] = zv0; zo[1] = zv1;
    if (f) {
        float* fo = (float*)dout + (size_t)u * 64 + o * 16;
        #pragma unroll
        for (int i = 0; i < 16; ++i) fo[i] = z[i];
    } else {
        uint4* bo = (uint4*)((u16*)dout + (size_t)u * 64 + o * 16);
        bo[0] = zv0; bo[1] = zv1;
    }
}

// ---------------- SAGE-layer GEMM: direct-fragment loads, no LDS, no barriers ----------------
// A fragments from [A1|A2] rows (row-major, 128 each); B fragments from Wt[n][K].
// Mode A (outB==null): out bf16 (+ optional out8 fp8). Mode B: colv<64 -> out8, else outB.
template <int K>
__global__ __launch_bounds__(256) void gemm_sage_kernel(
    const u16* __restrict__ A1, const u16* __restrict__ A2,
    const u16* __restrict__ Wt,
    const float* __restrict__ alpha, const float* __restrict__ beta,
    int addRes, u16* __restrict__ out, int ldo, u16* __restrict__ outB,
    u8* __restrict__ out8, int ld8,
    int M, int relu) {
    int tid = threadIdx.x;
    int mBase = blockIdx.x * 64, nBase = blockIdx.y * 64;
    int lane = tid & 63, w = tid >> 6;
    int wm = w >> 1, wn = w & 1;
    int q = lane >> 4, r = lane & 15;

    floatx4 acc[2][2];
    #pragma unroll
    for (int mi = 0; mi < 2; ++mi)
        #pragma unroll
        for (int ni = 0; ni < 2; ++ni)
            acc[mi][ni] = (floatx4){0.f, 0.f, 0.f, 0.f};

    int row0 = mBase + wm * 32 + r;          // mi=0 row
    int row1 = row0 + 16;                    // mi=1 row
    int r0c = min(row0, M - 1), r1c = min(row1, M - 1);
    const u16* bp = Wt + (size_t)(nBase + wn * 32 + r) * K + q * 8;

    #pragma unroll
    for (int k0 = 0; k0 < K; k0 += 32) {
        const u16* Abase = (k0 < 128) ? (A1 + k0) : (A2 + (k0 - 128));
        short8 af0 = *(const short8*)(Abase + (size_t)r0c * 128 + q * 8);
        short8 af1 = *(const short8*)(Abase + (size_t)r1c * 128 + q * 8);
        short8 bf0 = *(const short8*)(bp + k0);
        short8 bf1 = *(const short8*)(bp + 16 * K + k0);
        acc[0][0] = __builtin_amdgcn_mfma_f32_16x16x32_bf16(af0, bf0, acc[0][0], 0, 0, 0);
        acc[0][1] = __builtin_amdgcn_mfma_f32_16x16x32_bf16(af0, bf1, acc[0][1], 0, 0, 0);
        acc[1][0] = __builtin_amdgcn_mfma_f32_16x16x32_bf16(af1, bf0, acc[1][0], 0, 0, 0);
        acc[1][1] = __builtin_amdgcn_mfma_f32_16x16x32_bf16(af1, bf1, acc[1][1], 0, 0, 0);
    }

    #pragma unroll
    for (int mi = 0; mi < 2; ++mi)
        #pragma unroll
        for (int ni = 0; ni < 2; ++ni) {
            int colv = nBase + wn * 32 + ni * 16 + r;
            float al = alpha[colv], be = beta[colv];
            #pragma unroll
            for (int r4 = 0; r4 < 4; ++r4) {
                int row = mBase + wm * 32 + mi * 16 + q * 4 + r4;
                if (row < M) {
                    float v = acc[mi][ni][r4] * al + be;
                    if (relu) v = fmaxf(v, 0.0f);
                    if (addRes) v += b2f(A2[(size_t)row * 128 + colv]);
                    if (outB) {
                        if (colv < 64) out8[(size_t)row * 64 + colv] = f2e4m3(v);
                        else outB[(size_t)row * 64 + (colv - 64)] = f2b(v);
                    } else {
                        out[(size_t)row * ldo + colv] = f2b(v);
                        if (out8) out8[(size_t)row * ld8 + colv] = f2e4m3(v);
                    }
                }
            }
        }
}

// ---------------- fused edge decoder (64 edges/block, W from global) ----------------
__global__ __launch_bounds__(256) void decode_kernel(
    const u16* __restrict__ z,
    const int* __restrict__ sidx, const int* __restrict__ didx,
    const u16* __restrict__ Webt,              // [128][128] transposed
    const float* __restrict__ dparams,
    void* __restrict__ dout, long long outBase, int nE,
    const int* __restrict__ flags) {
    __shared__ u16 As[64 * 136];
    __shared__ float red[4][32];
    __shared__ float be1f[128], We2f[128];
    int tid = threadIdx.x;
    int f = flags[0];

    if (tid < 128) { be1f[tid] = dparams[tid]; We2f[tid] = dparams[128 + tid]; }

    int eBase = blockIdx.x * 64;
    {
        int row = tid >> 2, ch = tid & 3;
        int e = eBase + row;
        if (e >= nE) e = nE - 1;
        int node = (ch < 2) ? sidx[e] : didx[e];
        int off = (ch & 1) * 32;
        const short8* src = (const short8*)(z + (size_t)node * 64 + off);
        #pragma unroll
        for (int j = 0; j < 4; ++j)
            *(short8*)(&As[row * 136 + ch * 32 + j * 8]) = src[j];
    }
    __syncthreads();

    int lane = tid & 63, w = tid >> 6;
    int wm = w >> 1, wn = w & 1;
    int q = lane >> 4, r = lane & 15;
    floatx4 acc[2][4];
    #pragma unroll
    for (int mi = 0; mi < 2; ++mi)
        #pragma unroll
        for (int ni = 0; ni < 4; ++ni)
            acc[mi][ni] = (floatx4){0.f, 0.f, 0.f, 0.f};

    const u16* bp = Webt + (size_t)(wn * 64 + r) * 128 + q * 8;
    #pragma unroll
    for (int k0 = 0; k0 < 128; k0 += 32) {
        short8 af[2], bfv[4];
        #pragma unroll
        for (int mi = 0; mi < 2; ++mi)
            af[mi] = *(const short8*)(&As[(wm * 32 + mi * 16 + r) * 136 + k0 + q * 8]);
        #pragma unroll
        for (int ni = 0; ni < 4; ++ni)
            bfv[ni] = *(const short8*)(bp + (size_t)ni * 16 * 128 + k0);
        #pragma unroll
        for (int mi = 0; mi < 2; ++mi)
            #pragma unroll
            for (int ni = 0; ni < 4; ++ni)
                acc[mi][ni] = __builtin_amdgcn_mfma_f32_16x16x32_bf16(af[mi], bfv[ni], acc[mi][ni], 0, 0, 0);
    }

    float part[2][4] = {{0.f, 0.f, 0.f, 0.f}, {0.f, 0.f, 0.f, 0.f}};
    #pragma unroll
    for (int mi = 0; mi < 2; ++mi)
        #pragma unroll
        for (int ni = 0; ni < 4; ++ni) {
            int colv = wn * 64 + ni * 16 + r;
            float bb = be1f[colv], mm = We2f[colv];
            #pragma unroll
            for (int r4 = 0; r4 < 4; ++r4) {
                float v = acc[mi][ni][r4] + bb;
                part[mi][r4] += fmaxf(v, 0.0f) * mm;
            }
        }
    #pragma unroll
    for (int mi = 0; mi < 2; ++mi)
        #pragma unroll
        for (int r4 = 0; r4 < 4; ++r4) {
            float v = part[mi][r4];
            v += __shfl_xor(v, 1, 64);
            v += __shfl_xor(v, 2, 64);
            v += __shfl_xor(v, 4, 64);
            v += __shfl_xor(v, 8, 64);
            part[mi][r4] = v;
        }
    if (r == 0) {
        #pragma unroll
        for (int mi = 0; mi < 2; ++mi)
            #pragma unroll
            for (int r4 = 0; r4 < 4; ++r4)
                red[w][mi * 16 + q * 4 + r4] = part[mi][r4];
    }
    __syncthreads();
    if (tid < 64) {
        int e = eBase + tid;
        if (e < nE) {
            int half = tid >> 5, loc = tid & 31;
            float s = red[half * 2 + 0][loc] + red[half * 2 + 1][loc] + dparams[256];
            float sg = 1.0f / (1.0f + expf(-s));
            if (f) ((float*)dout)[outBase + e] = sg;
            else   ((u16*)dout)[outBase + e] = f2b(sg);
        }
    }
}

// ---------------- launch ----------------

extern "C" void kernel_launch(void* const* d_in, const int* in_sizes, int n_in,
                              void* d_out, int out_size, void* d_ws, size_t ws_size,
                              hipStream_t stream) {
    const void* x   = d_in[0];
    const int* ei   = (const int*)d_in[1];
    const int* pos  = (const int*)d_in[2];
    const int* neg  = (const int*)d_in[3];
    const void* Wl1 = d_in[4];
    const void* bl1 = d_in[5];
    const void* Wr1 = d_in[6];
    const void* g1  = d_in[7];
    const void* b1  = d_in[8];
    const void* Wl2 = d_in[9];
    const void* bl2 = d_in[10];
    const void* Wr2 = d_in[11];
    const void* g2  = d_in[12];
    const void* b2  = d_in[13];
    const void* Wl3 = d_in[14];
    const void* bl3 = d_in[15];
    const void* Wr3 = d_in[16];
    const void* We1 = d_in[17];
    const void* be1 = d_in[18];
    const void* We2 = d_in[19];
    const void* be2 = d_in[20];

    const int N = in_sizes[0] / 128;
    const int E = in_sizes[1] / 2;
    const int nPos = in_sizes[2] / 2;
    const int nNeg = in_sizes[3] / 2;
    const int nbuck = (N + 127) >> 7;
    const int EPB = (((E + 95) / 96) + 3) & ~3;
    const int B1 = (E + EPB - 1) / EPB;

    char* p = (char*)d_ws;
    auto alloc = [&](size_t bytes) -> void* {
        void* r = (void*)p;
        p += (bytes + 255) & ~(size_t)255;
        return r;
    };
    int*   flags     = (int*)alloc(64);
    int*   blockhist = (int*)alloc((size_t)nbuck * B1 * 4);
    int*   coltot    = (int*)alloc((size_t)nbuck * 4);
    int*   bucketbase= (int*)alloc((size_t)nbuck * 4);
    int*   rowptr    = (int*)alloc((size_t)(N + 1) * 4);
    int2*  pairs     = (int2*)alloc((size_t)E * 8);
    int*   colbuf    = (int*)alloc((size_t)E * 4);
    u16*   xb      = (u16*)alloc((size_t)N * 128 * 2);   // reused as hbufB
    u16*   hbufA   = (u16*)alloc((size_t)N * 128 * 2);   // reused as zbuf
    u16*   meanbuf = (u16*)alloc((size_t)N * 128 * 2);   // reused as ubuf
    u8*    x8      = (u8*)alloc((size_t)N * 128);
    u8*    h8      = (u8*)alloc((size_t)N * 128);
    u8*    t8      = (u8*)alloc((size_t)N * 64);
    u16*   W1t     = (u16*)alloc((size_t)128 * 256 * 2);
    u16*   W2t     = (u16*)alloc((size_t)128 * 256 * 2);
    u16*   W3t     = (u16*)alloc((size_t)128 * 128 * 2);
    u16*   Webt    = (u16*)alloc((size_t)128 * 128 * 2);
    float* al1 = (float*)alloc(128 * 4);
    float* bt1 = (float*)alloc(128 * 4);
    float* al2 = (float*)alloc(128 * 4);
    float* bt2 = (float*)alloc(128 * 4);
    float* al3 = (float*)alloc(128 * 4);
    float* bt3 = (float*)alloc(128 * 4);
    float* dparams = (float*)alloc(260 * 4);
    u16* hbufB = xb;
    u16* ubuf  = meanbuf + (size_t)N * 64;
    u16* zbuf  = hbufA + (size_t)N * 64;

    // dtype sniff + bucketed CSR build (no global atomics)
    sniff_kernel<<<1, 256, 0, stream>>>((const unsigned*)x, ei, flags);
    bucket_count_kernel<<<B1, 256, 0, stream>>>(ei, blockhist, E, EPB, B1, nbuck, flags);
    colscan_kernel<<<nbuck, 64, 0, stream>>>(blockhist, coltot, B1);
    base_scan_kernel<<<1, 1024, 0, stream>>>(coltot, bucketbase, rowptr + N, nbuck, E);
    bucket_scatter_kernel<<<B1, 256, 0, stream>>>(ei, bucketbase, blockhist, pairs, E, EPB, B1, nbuck, flags);
    bucket_csr_kernel<<<nbuck, 256, 0, stream>>>(pairs, bucketbase, coltot, rowptr, colbuf, N);

    // input / parameter conversion
    cvt_x_kernel<<<(N * 64 + 255) / 256, 256, 0, stream>>>(x, xb, (u16*)x8, flags, N * 64);
    prep_all_kernel<<<(98816 + 255) / 256, 256, 0, stream>>>(
        Wl1, Wr1, W1t, Wl2, Wr2, W2t, Wl3, Wr3, W3t, We1, Webt,
        g1, b1, bl1, al1, bt1, g2, b2, bl2, al2, bt2, bl3, al3, bt3,
        be1, We2, be2, dparams, flags);

    dim3 gemmGrid2((N + 63) / 64, 2);

    // layer 1
    aggregate_fp8_kernel<128><<<(N + 31) / 32, 256, 0, stream>>>(x8, rowptr, colbuf, meanbuf, N);
    gemm_sage_kernel<256><<<gemmGrid2, 256, 0, stream>>>(meanbuf, xb, W1t, al1, bt1,
                                                         1, hbufA, 128, nullptr, h8, 128, N, 1);
    // layer 2
    aggregate_fp8_kernel<128><<<(N + 31) / 32, 256, 0, stream>>>(h8, rowptr, colbuf, meanbuf, N);
    gemm_sage_kernel<256><<<gemmGrid2, 256, 0, stream>>>(meanbuf, hbufA, W2t, al2, bt2,
                                                         1, hbufB, 128, nullptr, nullptr, 0, N, 1);
    // layer 3 (commuted): [t|u] = h2@[Wl3|Wr3]; t -> t8 (fp8), u -> ubuf (bf16)
    gemm_sage_kernel<128><<<gemmGrid2, 256, 0, stream>>>(hbufB, hbufB, W3t, al3, bt3,
                                                         0, nullptr, 0, ubuf, t8, 64, N, 0);
    // z = mean(t8) + u -> zbuf + d_out
    agg_combine_kernel<<<(N + 63) / 64, 256, 0, stream>>>(t8, rowptr, colbuf, ubuf, zbuf,
                                                          d_out, N, flags);

    // decode pos / neg (64 edges/block)
    long long posBase = (long long)N * 64;
    long long negBase = posBase + nPos;
    decode_kernel<<<(nPos + 63) / 64, 256, 0, stream>>>(zbuf, pos, pos + nPos, Webt, dparams,
                                                        d_out, posBase, nPos, flags);
    decode_kernel<<<(nNeg + 63) / 64, 256, 0, stream>>>(zbuf, neg, neg + nNeg, Webt, dparams,
                                                        d_out, negBase, nNeg, flags);
}

// Round 10
// 502.388 us; speedup vs baseline: 1.0966x; 1.0966x over previous
//
#include <hip/hip_runtime.h>
#include <hip/hip_bf16.h>

typedef unsigned short u16;
typedef unsigned char u8;
typedef short short8 __attribute__((ext_vector_type(8)));
typedef float floatx4 __attribute__((ext_vector_type(4)));
typedef float floatx2 __attribute__((ext_vector_type(2)));

__device__ __forceinline__ float b2f(u16 u) {
    unsigned v = ((unsigned)u) << 16;
    float f;
    __builtin_memcpy(&f, &v, 4);
    return f;
}
__device__ __forceinline__ float b2f_lo(unsigned w) { return b2f((u16)(w & 0xffffu)); }
__device__ __forceinline__ float b2f_hi(unsigned w) { return b2f((u16)(w >> 16)); }
__device__ __forceinline__ u16 f2b(float f) {
    unsigned u;
    __builtin_memcpy(&u, &f, 4);
    u = u + 0x7fffu + ((u >> 16) & 1u);
    return (u16)(u >> 16);
}
__device__ __forceinline__ unsigned pack2(float a, float b) {
    return (unsigned)f2b(a) | ((unsigned)f2b(b) << 16);
}
__device__ __forceinline__ float loadp(const void* p, int i, int f) {
    return f ? ((const float*)p)[i] : b2f(((const u16*)p)[i]);
}
__device__ __forceinline__ u8 f2e4m3(float v) {
    int r = __builtin_amdgcn_cvt_pk_fp8_f32(v, v, 0, false);
    return (u8)(r & 0xff);
}
__device__ __forceinline__ void acc16_fp8(float* a, uint4 p) {
    floatx2 f;
    f = __builtin_amdgcn_cvt_pk_f32_fp8((int)p.x, false); a[0] += f[0];  a[1] += f[1];
    f = __builtin_amdgcn_cvt_pk_f32_fp8((int)p.x, true);  a[2] += f[0];  a[3] += f[1];
    f = __builtin_amdgcn_cvt_pk_f32_fp8((int)p.y, false); a[4] += f[0];  a[5] += f[1];
    f = __builtin_amdgcn_cvt_pk_f32_fp8((int)p.y, true);  a[6] += f[0];  a[7] += f[1];
    f = __builtin_amdgcn_cvt_pk_f32_fp8((int)p.z, false); a[8] += f[0];  a[9] += f[1];
    f = __builtin_amdgcn_cvt_pk_f32_fp8((int)p.z, true);  a[10] += f[0]; a[11] += f[1];
    f = __builtin_amdgcn_cvt_pk_f32_fp8((int)p.w, false); a[12] += f[0]; a[13] += f[1];
    f = __builtin_amdgcn_cvt_pk_f32_fp8((int)p.w, true);  a[14] += f[0]; a[15] += f[1];
}

// ---------------- dtype sniffing ----------------
__global__ void sniff_kernel(const unsigned* __restrict__ xw, const int* __restrict__ eiw,
                             int* __restrict__ flags) {
    __shared__ int s_fp32, s_i64;
    if (threadIdx.x == 0) { s_fp32 = 0; s_i64 = 1; }
    __syncthreads();
    int t = threadIdx.x;  // 256 threads
    unsigned w = xw[t];
    float lo = b2f_lo(w);
    if (!(fabsf(lo) <= 64.0f)) atomicOr(&s_fp32, 1);   // also catches NaN
    if (eiw[2 * t + 1] != 0) atomicAnd(&s_i64, 0);
    __syncthreads();
    if (t == 0) { flags[0] = s_fp32; flags[1] = s_i64; }
}

// ---------------- input conversion (bf16 + fp8 shadow) ----------------
__global__ void cvt_x_kernel(const void* __restrict__ x, u16* __restrict__ xb,
                             u16* __restrict__ x8,
                             const int* __restrict__ flags, int nPairs) {
    int f = flags[0];
    int i = blockIdx.x * 256 + threadIdx.x;
    if (i >= nPairs) return;
    float lo, hi;
    if (f) {
        float2 v = ((const float2*)x)[i];
        lo = v.x; hi = v.y;
        ((unsigned*)xb)[i] = pack2(lo, hi);
    } else {
        unsigned w = ((const unsigned*)x)[i];
        lo = b2f_lo(w); hi = b2f_hi(w);
        ((unsigned*)xb)[i] = w;
    }
    int r = __builtin_amdgcn_cvt_pk_fp8_f32(lo, hi, 0, false);
    x8[i] = (u16)(r & 0xffff);
}

// ---------------- fused parameter prep: all weights stored TRANSPOSED Wt[n][k] ----------------
__global__ void prep_all_kernel(const void* Wl1, const void* Wr1, u16* __restrict__ W1t,
                                const void* Wl2, const void* Wr2, u16* __restrict__ W2t,
                                const void* Wl3, const void* Wr3, u16* __restrict__ W3t,
                                const void* We1, u16* __restrict__ Webt,
                                const void* g1, const void* b1, const void* bl1,
                                float* __restrict__ al1, float* __restrict__ bt1,
                                const void* g2, const void* b2, const void* bl2,
                                float* __restrict__ al2, float* __restrict__ bt2,
                                const void* bl3,
                                float* __restrict__ al3, float* __restrict__ bt3,
                                const void* be1, const void* We2, const void* be2,
                                float* __restrict__ dparams,
                                const int* __restrict__ flags) {
    int f = flags[0];
    int idx = blockIdx.x * 256 + threadIdx.x;
    if (idx < 32768) {                       // W1t[n*256+k] = k<128 ? Wl1[k][n] : Wr1[k-128][n]
        int n = idx >> 8, k = idx & 255;
        const void* src = (k < 128) ? Wl1 : Wr1;
        int j = (k & 127) * 128 + n;
        W1t[idx] = f ? f2b(((const float*)src)[j]) : ((const u16*)src)[j];
    } else if (idx < 65536) {
        int i = idx - 32768;
        int n = i >> 8, k = i & 255;
        const void* src = (k < 128) ? Wl2 : Wr2;
        int j = (k & 127) * 128 + n;
        W2t[i] = f ? f2b(((const float*)src)[j]) : ((const u16*)src)[j];
    } else if (idx < 81920) {                // W3t[n*128+k]: n<64 from Wl3, else Wr3
        int i = idx - 65536;
        int n = i >> 7, k = i & 127;
        const void* src = (n < 64) ? Wl3 : Wr3;
        int j = k * 64 + (n & 63);
        W3t[i] = f ? f2b(((const float*)src)[j]) : ((const u16*)src)[j];
    } else if (idx < 98304) {                // Webt[n*128+k] = We1[k][n]
        int i = idx - 81920;
        int n = i >> 7, k = i & 127;
        int j = k * 128 + n;
        Webt[i] = f ? f2b(((const float*)We1)[j]) : ((const u16*)We1)[j];
    } else {
        int i = idx - 98304;
        if (i < 128) {
            float s = loadp(g1, i, f) * rsqrtf(1.0f + 1e-5f);
            al1[i] = s;
            bt1[i] = loadp(bl1, i, f) * s + loadp(b1, i, f);
        } else if (i < 256) {
            int j = i - 128;
            float s = loadp(g2, j, f) * rsqrtf(1.0f + 1e-5f);
            al2[j] = s;
            bt2[j] = loadp(bl2, j, f) * s + loadp(b2, j, f);
        } else if (i < 384) {
            int j = i - 256;
            al3[j] = 1.0f;
            bt3[j] = (j < 64) ? 0.0f : loadp(bl3, j - 64, f);
        } else if (i < 512) {
            int j = i - 384;
            dparams[j] = loadp(be1, j, f);
            dparams[128 + j] = loadp(We2, j, f);
            if (j == 0) dparams[256] = loadp(be2, 0, f);
        }
    }
}

// ---------------- CSR build: two-level counting sort (no global atomics) ----------------
__device__ __forceinline__ int edge_at(const int* ei, long long idx, int i64) {
    return i64 ? ei[2 * idx] : ei[idx];
}

__global__ __launch_bounds__(256) void bucket_count_kernel(const int* __restrict__ ei,
                                                           int* __restrict__ blockhist,
                                                           int E, int EPB, int B1, int nbuck,
                                                           const int* __restrict__ flags) {
    __shared__ int hist[1024];
    for (int i = threadIdx.x; i < nbuck; i += 256) hist[i] = 0;
    __syncthreads();
    int i64 = flags[1];
    int b = blockIdx.x;
    int lo = b * EPB, hi = min(lo + EPB, E);
    for (int e = lo + (int)threadIdx.x; e < hi; e += 256) {
        int d = edge_at(ei, (long long)E + e, i64);
        atomicAdd(&hist[d >> 7], 1);
    }
    __syncthreads();
    for (int k = threadIdx.x; k < nbuck; k += 256)
        blockhist[(size_t)k * B1 + b] = hist[k];
}

__global__ __launch_bounds__(64) void colscan_kernel(int* __restrict__ blockhist,
                                                     int* __restrict__ coltot, int B1) {
    int k = blockIdx.x, l = threadIdx.x;
    int* bh = blockhist + (size_t)k * B1;
    int x0 = (l < B1) ? bh[l] : 0;
    int x1 = (64 + l < B1) ? bh[64 + l] : 0;
    int s0 = x0;
    #pragma unroll
    for (int off = 1; off < 64; off <<= 1) {
        int u = __shfl_up(s0, off, 64);
        if (l >= off) s0 += u;
    }
    int tot0 = __shfl(s0, 63, 64);
    int s1 = x1;
    #pragma unroll
    for (int off = 1; off < 64; off <<= 1) {
        int u = __shfl_up(s1, off, 64);
        if (l >= off) s1 += u;
    }
    int tot1 = __shfl(s1, 63, 64);
    s1 += tot0;
    if (l < B1) bh[l] = s0 - x0;
    if (64 + l < B1) bh[64 + l] = s1 - x1;
    if (l == 0) coltot[k] = tot0 + tot1;
}

__global__ __launch_bounds__(1024) void base_scan_kernel(const int* __restrict__ coltot,
                                                         int* __restrict__ bucketbase,
                                                         int* __restrict__ rowptrN,
                                                         int nbuck, int E) {
    __shared__ int wsum[16];
    int t = threadIdx.x, lane = t & 63, w = t >> 6;
    int v = (t < nbuck) ? coltot[t] : 0;
    int inc = v;
    #pragma unroll
    for (int off = 1; off < 64; off <<= 1) {
        int u = __shfl_up(inc, off, 64);
        if (lane >= off) inc += u;
    }
    if (lane == 63) wsum[w] = inc;
    __syncthreads();
    int add = 0;
    for (int i = 0; i < w; ++i) add += wsum[i];
    if (t < nbuck) bucketbase[t] = add + inc - v;
    if (t == 0) rowptrN[0] = E;
}

__global__ __launch_bounds__(256) void bucket_scatter_kernel(const int* __restrict__ ei,
                                                             const int* __restrict__ bucketbase,
                                                             const int* __restrict__ blockhist,
                                                             int2* __restrict__ pairs,
                                                             int E, int EPB, int B1, int nbuck,
                                                             const int* __restrict__ flags) {
    __shared__ int off[1024];
    int b = blockIdx.x;
    for (int k = threadIdx.x; k < nbuck; k += 256)
        off[k] = bucketbase[k] + blockhist[(size_t)k * B1 + b];
    __syncthreads();
    int i64 = flags[1];
    int lo = b * EPB, hi = min(lo + EPB, E);
    for (int e = lo + (int)threadIdx.x; e < hi; e += 256) {
        int s = edge_at(ei, e, i64);
        int d = edge_at(ei, (long long)E + e, i64);
        int slot = atomicAdd(&off[d >> 7], 1);
        pairs[slot] = make_int2(s, d);
    }
}

__global__ __launch_bounds__(256) void bucket_csr_kernel(const int2* __restrict__ pairs,
                                                         const int* __restrict__ bucketbase,
                                                         const int* __restrict__ coltot,
                                                         int* __restrict__ rowptr,
                                                         int* __restrict__ col, int N) {
    __shared__ int srcs[4096];
    __shared__ unsigned char dl[4096];
    __shared__ int hist[128], cur[128];
    int k = blockIdx.x, tid = threadIdx.x;
    if (tid < 128) hist[tid] = 0;
    __syncthreads();
    int base = bucketbase[k], cnt = coltot[k];
    int staged = min(cnt, 4096);
    for (int i = tid; i < cnt; i += 256) {
        int2 pr = pairs[base + i];
        int j = pr.y & 127;
        atomicAdd(&hist[j], 1);
        if (i < 4096) { srcs[i] = pr.x; dl[i] = (unsigned char)j; }
    }
    __syncthreads();
    if (tid < 64) {
        int x0 = hist[tid], x1 = hist[64 + tid];
        int s0 = x0;
        #pragma unroll
        for (int off = 1; off < 64; off <<= 1) {
            int u = __shfl_up(s0, off, 64);
            if (tid >= off) s0 += u;
        }
        int tot0 = __shfl(s0, 63, 64);
        int s1 = x1;
        #pragma unroll
        for (int off = 1; off < 64; off <<= 1) {
            int u = __shfl_up(s1, off, 64);
            if (tid >= off) s1 += u;
        }
        s1 += tot0;
        cur[tid] = s0 - x0;
        cur[64 + tid] = s1 - x1;
    }
    __syncthreads();
    int node0 = k << 7;
    if (tid < 128 && node0 + tid < N) rowptr[node0 + tid] = base + cur[tid];
    __syncthreads();
    for (int i = tid; i < staged; i += 256) {
        int slot = base + atomicAdd(&cur[dl[i]], 1);
        col[slot] = srcs[i];
    }
    for (int i = 4096 + tid; i < cnt; i += 256) {
        int2 pr = pairs[base + i];
        int slot = base + atomicAdd(&cur[pr.y & 127], 1);
        col[slot] = pr.x;
    }
}

// ---------------- mean aggregation over fp8 rows -> bf16 means ----------------
template <int CH>
__global__ __launch_bounds__(256) void aggregate_fp8_kernel(const u8* __restrict__ X8,
                                                            const int* __restrict__ rowptr,
                                                            const int* __restrict__ col,
                                                            u16* __restrict__ meanout, int N) {
    constexpr int LPR = CH / 16;
    constexpr int GPB = 256 / LPR;
    int t = threadIdx.x;
    int g = t / LPR;
    int o = t % LPR;
    int u = blockIdx.x * GPB + g;
    if (u >= N) return;
    const uint4* Xv = (const uint4*)X8;
    int beg = rowptr[u], end = rowptr[u + 1];
    float a[16];
    #pragma unroll
    for (int i = 0; i < 16; ++i) a[i] = 0.f;
    int e = beg;
    for (; e + 4 <= end; e += 4) {
        int c0 = col[e], c1 = col[e + 1], c2 = col[e + 2], c3 = col[e + 3];
        uint4 p0 = Xv[(size_t)c0 * LPR + o];
        uint4 p1 = Xv[(size_t)c1 * LPR + o];
        uint4 p2 = Xv[(size_t)c2 * LPR + o];
        uint4 p3 = Xv[(size_t)c3 * LPR + o];
        acc16_fp8(a, p0); acc16_fp8(a, p1); acc16_fp8(a, p2); acc16_fp8(a, p3);
    }
    for (; e < end; ++e) {
        uint4 p = Xv[(size_t)col[e] * LPR + o];
        acc16_fp8(a, p);
    }
    int deg = end - beg;
    float inv = (deg > 0) ? 1.0f / (float)deg : 0.0f;
    uint4 ov0, ov1;
    ov0.x = pack2(a[0] * inv, a[1] * inv);   ov0.y = pack2(a[2] * inv, a[3] * inv);
    ov0.z = pack2(a[4] * inv, a[5] * inv);   ov0.w = pack2(a[6] * inv, a[7] * inv);
    ov1.x = pack2(a[8] * inv, a[9] * inv);   ov1.y = pack2(a[10] * inv, a[11] * inv);
    ov1.z = pack2(a[12] * inv, a[13] * inv); ov1.w = pack2(a[14] * inv, a[15] * inv);
    uint4* mo = (uint4*)meanout;
    mo[(size_t)u * (CH / 8) + o * 2 + 0] = ov0;
    mo[(size_t)u * (CH / 8) + o * 2 + 1] = ov1;
}

// ---------------- fused layer-3 tail: z = mean_fp8(t8) + u ----------------
__global__ __launch_bounds__(256) void agg_combine_kernel(const u8* __restrict__ T8,
                                                          const int* __restrict__ rowptr,
                                                          const int* __restrict__ col,
                                                          const u16* __restrict__ ubuf,
                                                          u16* __restrict__ zbuf,
                                                          void* __restrict__ dout,
                                                          int N, const int* __restrict__ flags) {
    constexpr int LPR = 4;
    constexpr int GPB = 64;
    int f = flags[0];
    int t = threadIdx.x;
    int g = t / LPR;
    int o = t % LPR;
    int u = blockIdx.x * GPB + g;
    if (u >= N) return;
    const uint4* Xv = (const uint4*)T8;
    int beg = rowptr[u], end = rowptr[u + 1];
    float a[16];
    #pragma unroll
    for (int i = 0; i < 16; ++i) a[i] = 0.f;
    int e = beg;
    for (; e + 4 <= end; e += 4) {
        int c0 = col[e], c1 = col[e + 1], c2 = col[e + 2], c3 = col[e + 3];
        uint4 p0 = Xv[(size_t)c0 * LPR + o];
        uint4 p1 = Xv[(size_t)c1 * LPR + o];
        uint4 p2 = Xv[(size_t)c2 * LPR + o];
        uint4 p3 = Xv[(size_t)c3 * LPR + o];
        acc16_fp8(a, p0); acc16_fp8(a, p1); acc16_fp8(a, p2); acc16_fp8(a, p3);
    }
    for (; e < end; ++e) {
        uint4 p = Xv[(size_t)col[e] * LPR + o];
        acc16_fp8(a, p);
    }
    int deg = end - beg;
    float inv = (deg > 0) ? 1.0f / (float)deg : 0.0f;
    const uint4* uv = (const uint4*)(ubuf + (size_t)u * 64 + o * 16);
    uint4 u0 = uv[0], u1 = uv[1];
    float z[16];
    z[0] = a[0] * inv + b2f_lo(u0.x);  z[1] = a[1] * inv + b2f_hi(u0.x);
    z[2] = a[2] * inv + b2f_lo(u0.y);  z[3] = a[3] * inv + b2f_hi(u0.y);
    z[4] = a[4] * inv + b2f_lo(u0.z);  z[5] = a[5] * inv + b2f_hi(u0.z);
    z[6] = a[6] * inv + b2f_lo(u0.w);  z[7] = a[7] * inv + b2f_hi(u0.w);
    z[8] = a[8] * inv + b2f_lo(u1.x);  z[9] = a[9] * inv + b2f_hi(u1.x);
    z[10] = a[10] * inv + b2f_lo(u1.y); z[11] = a[11] * inv + b2f_hi(u1.y);
    z[12] = a[12] * inv + b2f_lo(u1.z); z[13] = a[13] * inv + b2f_hi(u1.z);
    z[14] = a[14] * inv + b2f_lo(u1.w); z[15] = a[15] * inv + b2f_hi(u1.w);
    uint4 zv0, zv1;
    zv0.x = pack2(z[0], z[1]);   zv0.y = pack2(z[2], z[3]);
    zv0.z = pack2(z[4], z[5]);   zv0.w = pack2(z[6], z[7]);
    zv1.x = pack2(z[8], z[9]);   zv1.y = pack2(z[10], z[11]);
    zv1.z = pack2(z[12], z[13]); zv1.w = pack2(z[14], z[15]);
    uint4* zo = (uint4*)(zbuf + (size_t)u * 64 + o * 16);
    zo[0] = zv0; zo[1] = zv1;
    if (f) {
        float* fo = (float*)dout + (size_t)u * 64 + o * 16;
        #pragma unroll
        for (int i = 0; i < 16; ++i) fo[i] = z[i];
    } else {
        uint4* bo = (uint4*)((u16*)dout + (size_t)u * 64 + o * 16);
        bo[0] = zv0; bo[1] = zv1;
    }
}

// ---------------- SAGE-layer GEMM: 64x128 tile, LDS-staged, conflict-free ----------------
// A from [A1|A2] (row-major, 128 each); B staged from pre-transposed Wt[n][K] (straight copy).
// Mode A (outB==null): out bf16 (+ optional out8 fp8). Mode B: colv<64 -> out8, else outB.
#define LDA 40
template <int K>
__global__ __launch_bounds__(256) void gemm_sage_kernel(
    const u16* __restrict__ A1, const u16* __restrict__ A2,
    const u16* __restrict__ Wt,
    const float* __restrict__ alpha, const float* __restrict__ beta,
    int addRes, u16* __restrict__ out, int ldo, u16* __restrict__ outB,
    u8* __restrict__ out8, int ld8,
    int M, int relu) {
    __shared__ u16 As[64 * LDA];
    __shared__ u16 Bs[128 * LDA];
    int tid = threadIdx.x;
    int mBase = blockIdx.x * 64;
    int lane = tid & 63, w = tid >> 6;
    int wm = w >> 1, wn = w & 1;
    int q = lane >> 4, r = lane & 15;

    floatx4 acc[2][4];
    #pragma unroll
    for (int mi = 0; mi < 2; ++mi)
        #pragma unroll
        for (int ni = 0; ni < 4; ++ni)
            acc[mi][ni] = (floatx4){0.f, 0.f, 0.f, 0.f};

    int rowA = tid >> 2, kcA = (tid & 3) * 8;           // A tile: 64 rows x 32 k, 16B/lane
    int grA = min(mBase + rowA, M - 1);
    int nB = tid >> 1, kcB = (tid & 1) * 16;            // B tile: 128 rows x 32 k, 32B/lane

    for (int k0 = 0; k0 < K; k0 += 32) {
        const u16* Abase = (k0 < 128) ? (A1 + k0) : (A2 + (k0 - 128));
        *(short8*)(&As[rowA * LDA + kcA]) = *(const short8*)(Abase + (size_t)grA * 128 + kcA);
        const u16* bsrc = Wt + (size_t)nB * K + k0 + kcB;
        *(short8*)(&Bs[nB * LDA + kcB]) = *(const short8*)bsrc;
        *(short8*)(&Bs[nB * LDA + kcB + 8]) = *(const short8*)(bsrc + 8);
        __syncthreads();
        short8 af0 = *(const short8*)(&As[(wm * 32 + r) * LDA + q * 8]);
        short8 af1 = *(const short8*)(&As[(wm * 32 + 16 + r) * LDA + q * 8]);
        #pragma unroll
        for (int ni = 0; ni < 4; ++ni) {
            short8 bf = *(const short8*)(&Bs[(wn * 64 + ni * 16 + r) * LDA + q * 8]);
            acc[0][ni] = __builtin_amdgcn_mfma_f32_16x16x32_bf16(af0, bf, acc[0][ni], 0, 0, 0);
            acc[1][ni] = __builtin_amdgcn_mfma_f32_16x16x32_bf16(af1, bf, acc[1][ni], 0, 0, 0);
        }
        __syncthreads();
    }

    #pragma unroll
    for (int mi = 0; mi < 2; ++mi)
        #pragma unroll
        for (int ni = 0; ni < 4; ++ni) {
            int colv = wn * 64 + ni * 16 + r;
            float al = alpha[colv], be = beta[colv];
            #pragma unroll
            for (int r4 = 0; r4 < 4; ++r4) {
                int row = mBase + wm * 32 + mi * 16 + q * 4 + r4;
                if (row < M) {
                    float v = acc[mi][ni][r4] * al + be;
                    if (relu) v = fmaxf(v, 0.0f);
                    if (addRes) v += b2f(A2[(size_t)row * 128 + colv]);
                    if (outB) {
                        if (colv < 64) out8[(size_t)row * 64 + colv] = f2e4m3(v);
                        else outB[(size_t)row * 64 + (colv - 64)] = f2b(v);
                    } else {
                        out[(size_t)row * ldo + colv] = f2b(v);
                        if (out8) out8[(size_t)row * ld8 + colv] = f2e4m3(v);
                    }
                }
            }
        }
}

// ---------------- fused edge decoder (64 edges/block, W from global) ----------------
__global__ __launch_bounds__(256) void decode_kernel(
    const u16* __restrict__ z,
    const int* __restrict__ sidx, const int* __restrict__ didx,
    const u16* __restrict__ Webt,              // [128][128] transposed
    const float* __restrict__ dparams,
    void* __restrict__ dout, long long outBase, int nE,
    const int* __restrict__ flags) {
    __shared__ u16 As[64 * 136];
    __shared__ float red[4][32];
    __shared__ float be1f[128], We2f[128];
    int tid = threadIdx.x;
    int f = flags[0];

    if (tid < 128) { be1f[tid] = dparams[tid]; We2f[tid] = dparams[128 + tid]; }

    int eBase = blockIdx.x * 64;
    {
        int row = tid >> 2, ch = tid & 3;
        int e = eBase + row;
        if (e >= nE) e = nE - 1;
        int node = (ch < 2) ? sidx[e] : didx[e];
        int off = (ch & 1) * 32;
        const short8* src = (const short8*)(z + (size_t)node * 64 + off);
        #pragma unroll
        for (int j = 0; j < 4; ++j)
            *(short8*)(&As[row * 136 + ch * 32 + j * 8]) = src[j];
    }
    __syncthreads();

    int lane = tid & 63, w = tid >> 6;
    int wm = w >> 1, wn = w & 1;
    int q = lane >> 4, r = lane & 15;
    floatx4 acc[2][4];
    #pragma unroll
    for (int mi = 0; mi < 2; ++mi)
        #pragma unroll
        for (int ni = 0; ni < 4; ++ni)
            acc[mi][ni] = (floatx4){0.f, 0.f, 0.f, 0.f};

    const u16* bp = Webt + (size_t)(wn * 64 + r) * 128 + q * 8;
    #pragma unroll
    for (int k0 = 0; k0 < 128; k0 += 32) {
        short8 af[2], bfv[4];
        #pragma unroll
        for (int mi = 0; mi < 2; ++mi)
            af[mi] = *(const short8*)(&As[(wm * 32 + mi * 16 + r) * 136 + k0 + q * 8]);
        #pragma unroll
        for (int ni = 0; ni < 4; ++ni)
            bfv[ni] = *(const short8*)(bp + (size_t)ni * 16 * 128 + k0);
        #pragma unroll
        for (int mi = 0; mi < 2; ++mi)
            #pragma unroll
            for (int ni = 0; ni < 4; ++ni)
                acc[mi][ni] = __builtin_amdgcn_mfma_f32_16x16x32_bf16(af[mi], bfv[ni], acc[mi][ni], 0, 0, 0);
    }

    float part[2][4] = {{0.f, 0.f, 0.f, 0.f}, {0.f, 0.f, 0.f, 0.f}};
    #pragma unroll
    for (int mi = 0; mi < 2; ++mi)
        #pragma unroll
        for (int ni = 0; ni < 4; ++ni) {
            int colv = wn * 64 + ni * 16 + r;
            float bb = be1f[colv], mm = We2f[colv];
            #pragma unroll
            for (int r4 = 0; r4 < 4; ++r4) {
                float v = acc[mi][ni][r4] + bb;
                part[mi][r4] += fmaxf(v, 0.0f) * mm;
            }
        }
    #pragma unroll
    for (int mi = 0; mi < 2; ++mi)
        #pragma unroll
        for (int r4 = 0; r4 < 4; ++r4) {
            float v = part[mi][r4];
            v += __shfl_xor(v, 1, 64);
            v += __shfl_xor(v, 2, 64);
            v += __shfl_xor(v, 4, 64);
            v += __shfl_xor(v, 8, 64);
            part[mi][r4] = v;
        }
    if (r == 0) {
        #pragma unroll
        for (int mi = 0; mi < 2; ++mi)
            #pragma unroll
            for (int r4 = 0; r4 < 4; ++r4)
                red[w][mi * 16 + q * 4 + r4] = part[mi][r4];
    }
    __syncthreads();
    if (tid < 64) {
        int e = eBase + tid;
        if (e < nE) {
            int half = tid >> 5, loc = tid & 31;
            float s = red[half * 2 + 0][loc] + red[half * 2 + 1][loc] + dparams[256];
            float sg = 1.0f / (1.0f + expf(-s));
            if (f) ((float*)dout)[outBase + e] = sg;
            else   ((u16*)dout)[outBase + e] = f2b(sg);
        }
    }
}

// ---------------- launch ----------------

extern "C" void kernel_launch(void* const* d_in, const int* in_sizes, int n_in,
                              void* d_out, int out_size, void* d_ws, size_t ws_size,
                              hipStream_t stream) {
    const void* x   = d_in[0];
    const int* ei   = (const int*)d_in[1];
    const int* pos  = (const int*)d_in[2];
    const int* neg  = (const int*)d_in[3];
    const void* Wl1 = d_in[4];
    const void* bl1 = d_in[5];
    const void* Wr1 = d_in[6];
    const void* g1  = d_in[7];
    const void* b1  = d_in[8];
    const void* Wl2 = d_in[9];
    const void* bl2 = d_in[10];
    const void* Wr2 = d_in[11];
    const void* g2  = d_in[12];
    const void* b2  = d_in[13];
    const void* Wl3 = d_in[14];
    const void* bl3 = d_in[15];
    const void* Wr3 = d_in[16];
    const void* We1 = d_in[17];
    const void* be1 = d_in[18];
    const void* We2 = d_in[19];
    const void* be2 = d_in[20];

    const int N = in_sizes[0] / 128;
    const int E = in_sizes[1] / 2;
    const int nPos = in_sizes[2] / 2;
    const int nNeg = in_sizes[3] / 2;
    const int nbuck = (N + 127) >> 7;
    const int EPB = (((E + 95) / 96) + 3) & ~3;
    const int B1 = (E + EPB - 1) / EPB;

    char* p = (char*)d_ws;
    auto alloc = [&](size_t bytes) -> void* {
        void* r = (void*)p;
        p += (bytes + 255) & ~(size_t)255;
        return r;
    };
    int*   flags     = (int*)alloc(64);
    int*   blockhist = (int*)alloc((size_t)nbuck * B1 * 4);
    int*   coltot    = (int*)alloc((size_t)nbuck * 4);
    int*   bucketbase= (int*)alloc((size_t)nbuck * 4);
    int*   rowptr    = (int*)alloc((size_t)(N + 1) * 4);
    int2*  pairs     = (int2*)alloc((size_t)E * 8);
    int*   colbuf    = (int*)alloc((size_t)E * 4);
    u16*   xb      = (u16*)alloc((size_t)N * 128 * 2);   // reused as hbufB
    u16*   hbufA   = (u16*)alloc((size_t)N * 128 * 2);   // reused as zbuf
    u16*   meanbuf = (u16*)alloc((size_t)N * 128 * 2);   // reused as ubuf
    u8*    x8      = (u8*)alloc((size_t)N * 128);
    u8*    h8      = (u8*)alloc((size_t)N * 128);
    u8*    t8      = (u8*)alloc((size_t)N * 64);
    u16*   W1t     = (u16*)alloc((size_t)128 * 256 * 2);
    u16*   W2t     = (u16*)alloc((size_t)128 * 256 * 2);
    u16*   W3t     = (u16*)alloc((size_t)128 * 128 * 2);
    u16*   Webt    = (u16*)alloc((size_t)128 * 128 * 2);
    float* al1 = (float*)alloc(128 * 4);
    float* bt1 = (float*)alloc(128 * 4);
    float* al2 = (float*)alloc(128 * 4);
    float* bt2 = (float*)alloc(128 * 4);
    float* al3 = (float*)alloc(128 * 4);
    float* bt3 = (float*)alloc(128 * 4);
    float* dparams = (float*)alloc(260 * 4);
    u16* hbufB = xb;
    u16* ubuf  = meanbuf + (size_t)N * 64;
    u16* zbuf  = hbufA + (size_t)N * 64;

    // dtype sniff + bucketed CSR build (no global atomics)
    sniff_kernel<<<1, 256, 0, stream>>>((const unsigned*)x, ei, flags);
    bucket_count_kernel<<<B1, 256, 0, stream>>>(ei, blockhist, E, EPB, B1, nbuck, flags);
    colscan_kernel<<<nbuck, 64, 0, stream>>>(blockhist, coltot, B1);
    base_scan_kernel<<<1, 1024, 0, stream>>>(coltot, bucketbase, rowptr + N, nbuck, E);
    bucket_scatter_kernel<<<B1, 256, 0, stream>>>(ei, bucketbase, blockhist, pairs, E, EPB, B1, nbuck, flags);
    bucket_csr_kernel<<<nbuck, 256, 0, stream>>>(pairs, bucketbase, coltot, rowptr, colbuf, N);

    // input / parameter conversion
    cvt_x_kernel<<<(N * 64 + 255) / 256, 256, 0, stream>>>(x, xb, (u16*)x8, flags, N * 64);
    prep_all_kernel<<<(98816 + 255) / 256, 256, 0, stream>>>(
        Wl1, Wr1, W1t, Wl2, Wr2, W2t, Wl3, Wr3, W3t, We1, Webt,
        g1, b1, bl1, al1, bt1, g2, b2, bl2, al2, bt2, bl3, al3, bt3,
        be1, We2, be2, dparams, flags);

    int gemmGrid = (N + 63) / 64;

    // layer 1
    aggregate_fp8_kernel<128><<<(N + 31) / 32, 256, 0, stream>>>(x8, rowptr, colbuf, meanbuf, N);
    gemm_sage_kernel<256><<<gemmGrid, 256, 0, stream>>>(meanbuf, xb, W1t, al1, bt1,
                                                        1, hbufA, 128, nullptr, h8, 128, N, 1);
    // layer 2
    aggregate_fp8_kernel<128><<<(N + 31) / 32, 256, 0, stream>>>(h8, rowptr, colbuf, meanbuf, N);
    gemm_sage_kernel<256><<<gemmGrid, 256, 0, stream>>>(meanbuf, hbufA, W2t, al2, bt2,
                                                        1, hbufB, 128, nullptr, nullptr, 0, N, 1);
    // layer 3 (commuted): [t|u] = h2@[Wl3|Wr3]; t -> t8 (fp8), u -> ubuf (bf16)
    gemm_sage_kernel<128><<<gemmGrid, 256, 0, stream>>>(hbufB, hbufB, W3t, al3, bt3,
                                                        0, nullptr, 0, ubuf, t8, 64, N, 0);
    // z = mean(t8) + u -> zbuf + d_out
    agg_combine_kernel<<<(N + 63) / 64, 256, 0, stream>>>(t8, rowptr, colbuf, ubuf, zbuf,
                                                          d_out, N, flags);

    // decode pos / neg (64 edges/block)
    long long posBase = (long long)N * 64;
    long long negBase = posBase + nPos;
    decode_kernel<<<(nPos + 63) / 64, 256, 0, stream>>>(zbuf, pos, pos + nPos, Webt, dparams,
                                                        d_out, posBase, nPos, flags);
    decode_kernel<<<(nNeg + 63) / 64, 256, 0, stream>>>(zbuf, neg, neg + nNeg, Webt, dparams,
                                                        d_out, negBase, nNeg, flags);
}